// Round 4
// baseline (321.405 us; speedup 1.0000x reference)
//
#include <hip/hip_runtime.h>
#include <hip/hip_fp16.h>

// GAT 2-layer, N=100K, DIM=256, HID=16, NCLS=64, E=3.2M (+N self loops).
//  - CSR build: bucketed counting sort, PADDED buckets (bkt_cur seeded
//    b*CAPB) -> no pre-histogram; compact bases computed in p2 via an
//    in-block 512-scan of bkt_cur. Classic prescan fallback for small ws.
//  - p1 scatter: edges in registers, int4 edge loads, CHUNK=4096.
//  - h1 = x@W1 via MFMA f16 (16x16x32): 16-node tile/wave; depth-2 tile
//    pipeline with PLAIN loads fenced by sched_barrier(0) (R3 lesson:
//    asm+vmcnt(0) drains kill overlap; R1/R2: unfenced loads get sunk).
//    Epilogue waits lgkmcnt only (s_waitcnt 0 would drain the prefetch).
//  - node records are 64B: [h f16x16 | as f32 | pad] so the per-edge
//    alpha-source scalar and the h row share ONE cache line (halves the
//    random line-requests per edge in both agg kernels).
//  - p2 standalone (R3 fusion starved agg of occupancy: 782 waves total).
//  - agg: 16 lanes/node, 32-edge iterations, 4 row gathers hoisted.
//  - layer2 fused into agg2 (@W2 + b2 + log_softmax in-block).

#define DIM 256
#define HID 16
#define NCLS 64
#define NEG 0.2f
#define P1_CHUNK 4096
#define KITER 16
#define CAP 8704

typedef _Float16 f16x8 __attribute__((ext_vector_type(8)));
typedef float f32x4 __attribute__((ext_vector_type(4)));

__device__ __forceinline__ float lrelu(float v) { return v >= 0.f ? v : NEG * v; }

__device__ __forceinline__ uint4 pack_half8(const float* v) {
    __half2 p0 = __floats2half2_rn(v[0], v[1]);
    __half2 p1 = __floats2half2_rn(v[2], v[3]);
    __half2 p2 = __floats2half2_rn(v[4], v[5]);
    __half2 p3 = __floats2half2_rn(v[6], v[7]);
    return make_uint4(*(unsigned*)&p0, *(unsigned*)&p1, *(unsigned*)&p2, *(unsigned*)&p3);
}

__device__ __forceinline__ void unpack_half8(uint4 u, float* f) {
    float2 f0 = __half22float2(*(__half2*)&u.x);
    float2 f1 = __half22float2(*(__half2*)&u.y);
    float2 f2 = __half22float2(*(__half2*)&u.z);
    float2 f3 = __half22float2(*(__half2*)&u.w);
    f[0] = f0.x; f[1] = f0.y; f[2] = f1.x; f[3] = f1.y;
    f[4] = f2.x; f[5] = f2.y; f[6] = f3.x; f[7] = f3.y;
}

// Also zeroes bkt_cnt and seeds bkt_cur (replaces separate memsets).
__global__ void vsd_kernel(const float* __restrict__ W2, const float* __restrict__ as2,
                           const float* __restrict__ ad2, float* __restrict__ vsd,
                           int* __restrict__ bkt_cnt, int* __restrict__ bkt_cur, int capb) {
    int t = threadIdx.x;
    bkt_cnt[t] = 0;                       // 512 threads
    bkt_cur[t] = capb ? t * capb : 0;     // padded: fixed bucket bases
    if (t < 32) {
        int j = t & 15;
        const float* a = (t < 16) ? as2 : ad2;
        float s = 0.f;
        for (int c = 0; c < NCLS; ++c) s += W2[j * NCLS + c] * a[c];
        vsd[t] = s;
    }
}

// ---- CSR build ------------------------------------------------------------

// Classic-fallback pre-histogram (only when ws too small for padded coarse).
__global__ __launch_bounds__(256) void p0_hist(const int* __restrict__ dst, int E,
                                               int* __restrict__ bkt_cnt) {
    __shared__ int hist[512];
    int t = threadIdx.x;
    for (int i = t; i < 512; i += 256) hist[i] = 0;
    __syncthreads();
    int base = blockIdx.x * P1_CHUNK;
#pragma unroll
    for (int k = 0; k < KITER; ++k) {
        int idx = base + k * 256 + t;
        if (idx < E) atomicAdd(&hist[dst[idx] >> 8], 1);
    }
    __syncthreads();
    for (int i = t; i < 512; i += 256)
        if (hist[i]) atomicAdd(&bkt_cnt[i], hist[i]);
}

// classic fallback only: scan bkt_cnt -> bkt_base, bkt_cur=base (pre-p1).
__global__ void scanb(int* __restrict__ bkt_cnt, int* __restrict__ bkt_cur,
                      int* __restrict__ bkt_base, int nb) {
    __shared__ int lds[512];
    int t = threadIdx.x;
    int v = (t < nb) ? bkt_cnt[t] : 0;
    lds[t] = v;
    __syncthreads();
    for (int o = 1; o < 512; o <<= 1) {
        int x = (t >= o) ? lds[t - o] : 0;
        __syncthreads();
        lds[t] += x;
        __syncthreads();
    }
    if (t < nb) {
        int e = lds[t] - v;
        bkt_base[t] = e;
        bkt_cur[t] = e;
    }
}

// Fused p1_scatter + h1 MFMA, roles interleaved proportionally.
struct H1S {
    _Float16 w1t[16][264];    // W1^T f16, padded row stride (528B, 16B-mult)
    _Float16 hst[4][16][16];  // per-wave row staging for packed writeout
};

__global__ __launch_bounds__(256) void p1h1_kernel(
    const int* __restrict__ ei, int E, int* __restrict__ bkt_cur,
    int* __restrict__ coarse, int nS, int h1blk, int capb,
    const float* __restrict__ x, const float* __restrict__ W1,
    const float* __restrict__ asw, const float* __restrict__ adw,
    uint4* __restrict__ h1h, float* __restrict__ ad1, int n) {
    __shared__ union __align__(16) { int hist[512]; H1S h1; } sm;
    int t = threadIdx.x;
    int bid = blockIdx.x;
    int total = nS + h1blk;
    // proportional role interleave: block bid is an h1 block iff
    // floor((bid+1)*h1blk/total) > floor(bid*h1blk/total).
    int f0 = (int)(((long long)bid * h1blk) / total);
    int f1 = (int)(((long long)(bid + 1) * h1blk) / total);
    if (f1 == f0) {
        // ---------------- p1 scatter (edges in registers) ----------------
        int sb = bid - f0;
        int base = sb * P1_CHUNK;
        int sarr[KITER], darr[KITER];
        for (int i = t; i < 512; i += 256) sm.hist[i] = 0;
        bool e4 = ((E & 3) == 0);
#pragma unroll
        for (int k = 0; k < KITER / 4; ++k) {
            int idx = base + (k * 256 + t) * 4;
            if (e4 && idx + 3 < E) {
                int4 s4 = *(const int4*)&ei[idx];
                int4 d4 = *(const int4*)&ei[E + idx];
                sarr[4 * k] = s4.x; sarr[4 * k + 1] = s4.y;
                sarr[4 * k + 2] = s4.z; sarr[4 * k + 3] = s4.w;
                darr[4 * k] = d4.x; darr[4 * k + 1] = d4.y;
                darr[4 * k + 2] = d4.z; darr[4 * k + 3] = d4.w;
            } else {
#pragma unroll
                for (int j = 0; j < 4; ++j) {
                    int id2 = idx + j;
                    if (id2 < E) { sarr[4 * k + j] = ei[id2]; darr[4 * k + j] = ei[E + id2]; }
                    else darr[4 * k + j] = -1;
                }
            }
        }
        __syncthreads();
#pragma unroll
        for (int k = 0; k < KITER; ++k)
            if (darr[k] >= 0) atomicAdd(&sm.hist[darr[k] >> 8], 1);
        __syncthreads();
        for (int b = t; b < 512; b += 256) {
            int c = sm.hist[b];
            sm.hist[b] = c ? atomicAdd(&bkt_cur[b], c) : 0;
        }
        __syncthreads();
#pragma unroll
        for (int k = 0; k < KITER; ++k) {
            int d = darr[k];
            if (d >= 0) {
                int bk = d >> 8;
                int pos = atomicAdd(&sm.hist[bk], 1);
                if (capb) pos = min(pos, (bk + 1) * capb - 1);  // unreachable guard
                coarse[pos] = (sarr[k] << 8) | (d & 255);
            }
        }
    } else {
        // ---------------- h1 MFMA (depth-2 tile pipeline) ----------------
        int hb = f0;
        {
            const float* row = W1 + t * HID;  // t = k index 0..255
#pragma unroll
            for (int nn2 = 0; nn2 < 16; ++nn2)
                sm.h1.w1t[nn2][t] = (_Float16)row[nn2];
        }
        __syncthreads();
        int lane = t & 63, wave = t >> 6;
        int q = lane >> 4, nn = lane & 15;
        float asv = asw[nn], adv = adw[nn];

        float4 st0[16], st1[16];
        auto ISSUE = [&](float4 (&st)[16], int it) {
            int nb = hb * 256 + wave * 64 + it * 16;
            int node = nb + nn;
            const float* xr = x + (size_t)min(node, n - 1) * DIM;
#pragma unroll
            for (int s = 0; s < 8; ++s) {
                int kb = s * 32 + q * 8;
                st[2 * s]     = *(const float4*)(xr + kb);
                st[2 * s + 1] = *(const float4*)(xr + kb + 4);
            }
        };
        auto COMPUTE = [&](const float4 (&st)[16], int it) {
            int nb = hb * 256 + wave * 64 + it * 16;
            f32x4 acc = {0.f, 0.f, 0.f, 0.f};
#pragma unroll
            for (int s = 0; s < 8; ++s) {
                int kb = s * 32 + q * 8;
                f16x8 bf = *(const f16x8*)&sm.h1.w1t[nn][kb];
                float4 a0 = st[2 * s], a1 = st[2 * s + 1];
                f16x8 af;
                af[0] = (_Float16)a0.x; af[1] = (_Float16)a0.y;
                af[2] = (_Float16)a0.z; af[3] = (_Float16)a0.w;
                af[4] = (_Float16)a1.x; af[5] = (_Float16)a1.y;
                af[6] = (_Float16)a1.z; af[7] = (_Float16)a1.w;
                acc = __builtin_amdgcn_mfma_f32_16x16x32_f16(af, bf, acc, 0, 0, 0);
            }
            if (nb < n) {  // wave-uniform
                // D[row=q*4+r][col=nn]; row = node-in-tile, col = j.
#pragma unroll
                for (int r = 0; r < 4; ++r) {
                    float v = acc[r];
                    sm.h1.hst[wave][q * 4 + r][nn] = (_Float16)v;
                    float t1 = v * asv, t2 = v * adv;
#pragma unroll
                    for (int mm = 1; mm < 16; mm <<= 1) {
                        t1 += __shfl_xor(t1, mm, 64);
                        t2 += __shfl_xor(t2, mm, 64);
                    }
                    if (nn == 0) {
                        int nd = nb + q * 4 + r;
                        if (nd < n) {
                            ((float*)(h1h + (size_t)nd * 4))[8] = t1;  // as in row
                            ad1[nd] = t2;
                        }
                    }
                }
                // drain LDS only (NOT vmcnt: next tile's loads are in flight)
                asm volatile("s_waitcnt lgkmcnt(0)" ::: "memory");
                if (lane < 32) {
                    int nl = lane >> 1, jq = lane & 1;
                    int nd = nb + nl;
                    if (nd < n)
                        h1h[(size_t)nd * 4 + jq] = *(const uint4*)&sm.h1.hst[wave][nl][jq * 8];
                }
            }
        };
        ISSUE(st0, 0);
        __builtin_amdgcn_sched_barrier(0);
        ISSUE(st1, 1);
        __builtin_amdgcn_sched_barrier(0);
        COMPUTE(st0, 0);
        __builtin_amdgcn_sched_barrier(0);
        ISSUE(st0, 2);
        __builtin_amdgcn_sched_barrier(0);
        COMPUTE(st1, 1);
        __builtin_amdgcn_sched_barrier(0);
        ISSUE(st1, 3);
        __builtin_amdgcn_sched_barrier(0);
        COMPUTE(st0, 2);
        __builtin_amdgcn_sched_barrier(0);
        COMPUTE(st1, 3);
    }
}

// p2: per-bucket fine sort staged in LDS -> coalesced csr writeout.
// 512 threads; capb path computes compact bases via in-block scan of bkt_cur.
__global__ __launch_bounds__(512) void p2_fine(const int* __restrict__ coarse,
                                               const int* __restrict__ bkt_base,
                                               const int* __restrict__ bkt_cnt,
                                               const int* __restrict__ bkt_cur,
                                               int* __restrict__ csr, int* __restrict__ row_ptr,
                                               int* __restrict__ deg, int n, int capb) {
    __shared__ int cnt[256];
    __shared__ int off[256];
    __shared__ int csr_loc[CAP];
    int b = blockIdx.x;
    int t = threadIdx.x;
    int m, wbase;
    if (capb) {
        // in-block exclusive scan of per-bucket counts (all 512 buckets)
        int* sc = csr_loc;  // reuse before sort phase
        int cv = bkt_cur[t] - t * capb;
        sc[t] = cv;
        __syncthreads();
        for (int o = 1; o < 512; o <<= 1) {
            int xg = (t >= o) ? sc[t - o] : 0;
            __syncthreads();
            sc[t] += xg;
            __syncthreads();
        }
        m = bkt_cur[b] - b * capb;
        wbase = sc[b] - m;
        __syncthreads();
    } else {
        m = bkt_cnt[b];
        wbase = bkt_base[b];
    }
    int rbase = capb ? b * capb : wbase;
    if (t < 256) cnt[t] = 0;
    __syncthreads();
    for (int i = t; i < m; i += 512) atomicAdd(&cnt[coarse[rbase + i] & 255], 1);
    __syncthreads();
    int v = 0;
    if (t < 256) { v = cnt[t]; off[t] = v; }
    __syncthreads();
    for (int o = 1; o < 256; o <<= 1) {
        int xg = (t >= o && t < 256) ? off[t - o] : 0;
        __syncthreads();
        if (t < 256) off[t] += xg;
        __syncthreads();
    }
    if (t < 256) {
        int excl = off[t] - v;
        int node = b * 256 + t;
        if (node < n) {
            row_ptr[node] = wbase + excl;
            deg[node] = v;
        }
        cnt[t] = excl;  // local cursor
    }
    __syncthreads();
    if (m <= CAP) {
        for (int i = t; i < m; i += 512) {
            int rec = coarse[rbase + i];
            int pos = atomicAdd(&cnt[rec & 255], 1);
            csr_loc[pos] = rec >> 8;
        }
        __syncthreads();
        for (int i = t; i < m; i += 512) csr[wbase + i] = csr_loc[i];
    } else {  // never expected; correctness fallback
        for (int i = t; i < m; i += 512) {
            int rec = coarse[rbase + i];
            int pos = atomicAdd(&cnt[rec & 255], 1);
            csr[wbase + pos] = rec >> 8;
        }
    }
}

// ---- aggregation core -----------------------------------------------------

// Node record: 64B = [h f16x16 | as f32 | pad]. hh stride = 4 uint4.
// 16 lanes/node = (eq 0..7 edge-slot) x (jq 0..1 row-half); 32-edge
// iterations, 4 hoisted row gathers per lane per iteration. The per-edge
// as fetch (word 8 of the row) warms the SAME line the row gathers hit.
__device__ __forceinline__ void agg_core(
    const uint4* __restrict__ hh, float adi,
    int node, int start, int cnt, const int* __restrict__ csr,
    int lg, int eq, int jq, int gbase, float* acc, float& denomv) {
    const float* hhf = (const float*)hh;
    float asn = hhf[(size_t)node * 16 + 8];
    float w0 = __expf(lrelu(asn + adi));
    float w0s = (eq == 0) ? w0 : 0.f;
    float hs[8];
    unpack_half8(hh[(size_t)node * 4 + jq], hs);
#pragma unroll
    for (int i = 0; i < 8; ++i) acc[i] = w0s * hs[i];
    float denom = w0s;
#pragma unroll 1
    for (int q0 = 0; q0 < cnt; q0 += 32) {
        int i0 = q0 + lg, i1 = q0 + 16 + lg;
        int svA = (i0 < cnt) ? csr[start + i0] : 0;
        int svB = (i1 < cnt) ? csr[start + i1] : 0;
        float avA = hhf[(size_t)svA * 16 + 8];
        float avB = hhf[(size_t)svB * 16 + 8];
        float wvA = (i0 < cnt) ? __expf(lrelu(avA + adi)) : 0.f;
        float wvB = (i1 < cnt) ? __expf(lrelu(avB + adi)) : 0.f;
        int sl0 = gbase + eq, sl1 = gbase + 8 + eq;
        int s0 = __shfl(svA, sl0, 64);
        int s1 = __shfl(svA, sl1, 64);
        int s2 = __shfl(svB, sl0, 64);
        int s3 = __shfl(svB, sl1, 64);
        float wA = __shfl(wvA, sl0, 64);
        float wB = __shfl(wvA, sl1, 64);
        float wC = __shfl(wvB, sl0, 64);
        float wD = __shfl(wvB, sl1, 64);
        uint4 u0 = hh[(size_t)s0 * 4 + jq];
        uint4 u1 = hh[(size_t)s1 * 4 + jq];
        uint4 u2 = hh[(size_t)s2 * 4 + jq];
        uint4 u3 = hh[(size_t)s3 * 4 + jq];
        denom += wA + wB + wC + wD;
        float h0[8], h1v[8], h2[8], h3[8];
        unpack_half8(u0, h0);
        unpack_half8(u1, h1v);
        unpack_half8(u2, h2);
        unpack_half8(u3, h3);
#pragma unroll
        for (int i = 0; i < 8; ++i)
            acc[i] += wA * h0[i] + wB * h1v[i] + wC * h2[i] + wD * h3[i];
    }
#pragma unroll
    for (int m = 2; m <= 8; m <<= 1) {
#pragma unroll
        for (int i = 0; i < 8; ++i) acc[i] += __shfl_xor(acc[i], m, 64);
        denom += __shfl_xor(denom, m, 64);
    }
    denomv = denom;
}

__global__ __launch_bounds__(256) void agg1_kernel(
    const uint4* __restrict__ hh, const float* __restrict__ ad,
    const int* __restrict__ row_ptr, const int* __restrict__ deg, const int* __restrict__ csr,
    const float* __restrict__ bias, const float* __restrict__ vsd,
    uint4* __restrict__ outh, float* __restrict__ ad_out, int n) {
    int t = threadIdx.x;
    int node = blockIdx.x * 16 + (t >> 4);
    if (node >= n) return;
    int lg = t & 15, jq = lg & 1, eq = lg >> 1, gbase = t & 48;
    float adi = ad[node];
    float acc[8];
    float denom;
    agg_core(hh, adi, node, row_ptr[node], deg[node], csr, lg, eq, jq, gbase, acc, denom);
    float inv = 1.f / denom;
    const float* bj = bias + jq * 8;
    float val[8];
#pragma unroll
    for (int i = 0; i < 8; ++i) val[i] = fmaxf(acc[i] * inv + bj[i], 0.f);
    if (eq == 0) outh[(size_t)node * 4 + jq] = pack_half8(val);
    const float* vs = vsd + jq * 8;
    const float* vd = vsd + 16 + jq * 8;
    float t1 = 0.f, t2 = 0.f;
#pragma unroll
    for (int i = 0; i < 8; ++i) { t1 += val[i] * vs[i]; t2 += val[i] * vd[i]; }
    t1 += __shfl_xor(t1, 1, 64);
    t2 += __shfl_xor(t2, 1, 64);
    if (lg == 0) {
        ((float*)(outh + (size_t)node * 4))[8] = t1;  // as2 in row
        ad_out[node] = t2;
    }
}

__global__ __launch_bounds__(256) void agg2_final_kernel(
    const uint4* __restrict__ hh, const float* __restrict__ ad,
    const int* __restrict__ row_ptr, const int* __restrict__ deg, const int* __restrict__ csr,
    const float* __restrict__ W2, const float* __restrict__ b2,
    float* __restrict__ out, int n) {
    __shared__ float a2s[16 * HID];
    __shared__ float w2s[HID * NCLS];
    __shared__ float b2s[NCLS];
    int t = threadIdx.x;
    for (int i = t; i < HID * NCLS; i += 256) w2s[i] = W2[i];
    if (t < NCLS) b2s[t] = b2[t];
    int g = t >> 4;
    int node = blockIdx.x * 16 + g;
    int lg = t & 15, jq = lg & 1, eq = lg >> 1, gbase = t & 48;
    if (node < n) {
        float adi = ad[node];
        float acc[8];
        float denom;
        agg_core(hh, adi, node, row_ptr[node], deg[node], csr, lg, eq, jq, gbase, acc, denom);
        float inv = 1.f / denom;
        if (eq == 0) {
            float* dst = &a2s[g * HID + jq * 8];
            *(float4*)dst = make_float4(acc[0] * inv, acc[1] * inv, acc[2] * inv, acc[3] * inv);
            *(float4*)(dst + 4) = make_float4(acc[4] * inv, acc[5] * inv, acc[6] * inv, acc[7] * inv);
        }
    }
    __syncthreads();
    int wv = t >> 6;
    int c = t & 63;
#pragma unroll
    for (int i = 0; i < 4; ++i) {
        int nl = i * 4 + wv;
        int gn = blockIdx.x * 16 + nl;
        if (gn >= n) continue;
        const float* ar = &a2s[nl * HID];
        float v = b2s[c];
#pragma unroll
        for (int j = 0; j < HID; ++j) v += ar[j] * w2s[j * NCLS + c];
        float mx = v;
#pragma unroll
        for (int off = 1; off < 64; off <<= 1) mx = fmaxf(mx, __shfl_xor(mx, off, 64));
        float ex = __expf(v - mx);
        float s = ex;
#pragma unroll
        for (int off = 1; off < 64; off <<= 1) s += __shfl_xor(s, off, 64);
        out[(size_t)gn * NCLS + c] = (v - mx) - __logf(s);
    }
}

extern "C" void kernel_launch(void* const* d_in, const int* in_sizes, int n_in,
                              void* d_out, int out_size, void* d_ws, size_t ws_size,
                              hipStream_t stream) {
    const float* x    = (const float*)d_in[0];
    const int*   ei   = (const int*)d_in[1];  // [2,E]: [0..E)=src, [E..2E)=dst
    const float* W1   = (const float*)d_in[2];
    const float* a_s1 = (const float*)d_in[3];
    const float* a_d1 = (const float*)d_in[4];
    const float* b1   = (const float*)d_in[5];
    const float* W2   = (const float*)d_in[6];
    const float* a_s2 = (const float*)d_in[7];
    const float* a_d2 = (const float*)d_in[8];
    const float* b2   = (const float*)d_in[9];
    float* out = (float*)d_out;

    const int N = in_sizes[0] / DIM;
    const int E = in_sizes[1] / 2;
    const int NB = (N + 255) >> 8;
    const int nS = (E + P1_CHUNK - 1) / P1_CHUNK;
    const int h1blk = (N + 255) / 256;

    char* p = (char*)d_ws;
    auto alloc = [&](size_t bytes) {
        char* r = p;
        p += (bytes + 255) & ~(size_t)255;
        return r;
    };
    int*   bkt_cnt  = (int*)alloc(512 * 4);
    int*   bkt_base = (int*)alloc(512 * 4);
    int*   bkt_cur  = (int*)alloc(512 * 4);
    int*   csr      = (int*)alloc((size_t)E * 4);
    int*   row_ptr  = (int*)alloc((size_t)N * 4);
    int*   deg      = (int*)alloc((size_t)N * 4);
    float* ad1      = (float*)alloc((size_t)N * 4);
    float* ad2      = (float*)alloc((size_t)N * 4);
    float* vsd      = (float*)alloc(32 * 4);
    uint4* h1h      = (uint4*)alloc((size_t)N * 64);   // 64B node records
    uint4* hreluh   = (uint4*)alloc((size_t)N * 64);

    // coarse buffer: padded layout (no pre-histogram) if workspace allows.
    int capb = 10240;  // mean bucket ~8192, sd ~90 -> 22 sigma headroom
    size_t used = (size_t)(p - (char*)d_ws);
    size_t pad_bytes = (size_t)512 * capb * 4;
    int* coarse;
    if (ws_size - used >= pad_bytes) {
        coarse = (int*)alloc(pad_bytes);
    } else {
        capb = 0;  // classic prescan fallback
        coarse = (int*)alloc((size_t)E * 4);
    }

    vsd_kernel<<<1, 512, 0, stream>>>(W2, a_s2, a_d2, vsd, bkt_cnt, bkt_cur, capb);
    if (!capb) {
        p0_hist<<<nS, 256, 0, stream>>>(ei + E, E, bkt_cnt);
        scanb<<<1, 512, 0, stream>>>(bkt_cnt, bkt_cur, bkt_base, NB);
    }
    p1h1_kernel<<<nS + h1blk, 256, 0, stream>>>(ei, E, bkt_cur, coarse, nS, h1blk, capb,
                                                x, W1, a_s1, a_d1, h1h, ad1, N);
    p2_fine<<<NB, 512, 0, stream>>>(coarse, bkt_base, bkt_cnt, bkt_cur,
                                    csr, row_ptr, deg, N, capb);
    agg1_kernel<<<(N + 15) / 16, 256, 0, stream>>>(h1h, ad1, row_ptr, deg, csr,
                                                   b1, vsd, hreluh, ad2, N);
    agg2_final_kernel<<<(N + 15) / 16, 256, 0, stream>>>(hreluh, ad2, row_ptr, deg, csr,
                                                         W2, b2, out, N);
}

// Round 5
// 299.850 us; speedup vs baseline: 1.0719x; 1.0719x over previous
//
#include <hip/hip_runtime.h>
#include <hip/hip_fp16.h>

// GAT 2-layer, N=100K, DIM=256, HID=16, NCLS=64, E=3.2M (+N self loops).
//  - CSR build: bucketed counting sort, PADDED buckets (bkt_cur seeded
//    b*CAPB) -> no pre-histogram; compact bases computed in p2 via an
//    in-block 512-scan of bkt_cur. Classic prescan fallback for small ws.
//  - p1 scatter: edges in registers, int4 edge loads, CHUNK=4096 (R2).
//  - h1 = x@W1 via MFMA f16 (16x16x32): 16-node tile/wave, plain staged
//    loads (R2-proven ~69us; R3 asm drains and R4 sched_barrier pipeline
//    both regressed). Epilogue writes ONLY the 32B h record (no as/ad).
//  - agg: RECOMPUTE-as scheme. Per edge, as[s] = h[s].a_s is an 8-FMA
//    half-dot on the row we gather anyway + shfl_xor(1) -- removes the
//    separate as[] gather (was ~half of all random line-requests) and
//    all as/ad side arrays. Gather working set 3.2MB -> L2-resident
//    (R4 lesson: 64B records = 6.4MB blew the 4MB XCD L2).
//  - 32-edge iterations, 4 row gathers hoisted, csr prefetched.
//  - layer2 fused into agg2: as2/ad2 from vsd-dots on the relu record;
//    @W2 + b2 + log_softmax in-block.

#define DIM 256
#define HID 16
#define NCLS 64
#define NEG 0.2f
#define P1_CHUNK 4096
#define KITER 16
#define CAP 8704

typedef _Float16 f16x8 __attribute__((ext_vector_type(8)));
typedef float f32x4 __attribute__((ext_vector_type(4)));

__device__ __forceinline__ float lrelu(float v) { return v >= 0.f ? v : NEG * v; }

__device__ __forceinline__ uint4 pack_half8(const float* v) {
    __half2 p0 = __floats2half2_rn(v[0], v[1]);
    __half2 p1 = __floats2half2_rn(v[2], v[3]);
    __half2 p2 = __floats2half2_rn(v[4], v[5]);
    __half2 p3 = __floats2half2_rn(v[6], v[7]);
    return make_uint4(*(unsigned*)&p0, *(unsigned*)&p1, *(unsigned*)&p2, *(unsigned*)&p3);
}

__device__ __forceinline__ void unpack_half8(uint4 u, float* f) {
    float2 f0 = __half22float2(*(__half2*)&u.x);
    float2 f1 = __half22float2(*(__half2*)&u.y);
    float2 f2 = __half22float2(*(__half2*)&u.z);
    float2 f3 = __half22float2(*(__half2*)&u.w);
    f[0] = f0.x; f[1] = f0.y; f[2] = f1.x; f[3] = f1.y;
    f[4] = f2.x; f[5] = f2.y; f[6] = f3.x; f[7] = f3.y;
}

// Also zeroes bkt_cnt and seeds bkt_cur (replaces separate memsets).
__global__ void vsd_kernel(const float* __restrict__ W2, const float* __restrict__ as2,
                           const float* __restrict__ ad2, float* __restrict__ vsd,
                           int* __restrict__ bkt_cnt, int* __restrict__ bkt_cur, int capb) {
    int t = threadIdx.x;
    bkt_cnt[t] = 0;                       // 512 threads
    bkt_cur[t] = capb ? t * capb : 0;     // padded: fixed bucket bases
    if (t < 32) {
        int j = t & 15;
        const float* a = (t < 16) ? as2 : ad2;
        float s = 0.f;
        for (int c = 0; c < NCLS; ++c) s += W2[j * NCLS + c] * a[c];
        vsd[t] = s;
    }
}

// ---- CSR build ------------------------------------------------------------

// Classic-fallback pre-histogram (only when ws too small for padded coarse).
__global__ __launch_bounds__(256) void p0_hist(const int* __restrict__ dst, int E,
                                               int* __restrict__ bkt_cnt) {
    __shared__ int hist[512];
    int t = threadIdx.x;
    for (int i = t; i < 512; i += 256) hist[i] = 0;
    __syncthreads();
    int base = blockIdx.x * P1_CHUNK;
#pragma unroll
    for (int k = 0; k < KITER; ++k) {
        int idx = base + k * 256 + t;
        if (idx < E) atomicAdd(&hist[dst[idx] >> 8], 1);
    }
    __syncthreads();
    for (int i = t; i < 512; i += 256)
        if (hist[i]) atomicAdd(&bkt_cnt[i], hist[i]);
}

// classic fallback only: scan bkt_cnt -> bkt_base, bkt_cur=base (pre-p1).
__global__ void scanb(int* __restrict__ bkt_cnt, int* __restrict__ bkt_cur,
                      int* __restrict__ bkt_base, int nb) {
    __shared__ int lds[512];
    int t = threadIdx.x;
    int v = (t < nb) ? bkt_cnt[t] : 0;
    lds[t] = v;
    __syncthreads();
    for (int o = 1; o < 512; o <<= 1) {
        int x = (t >= o) ? lds[t - o] : 0;
        __syncthreads();
        lds[t] += x;
        __syncthreads();
    }
    if (t < nb) {
        int e = lds[t] - v;
        bkt_base[t] = e;
        bkt_cur[t] = e;
    }
}

// Fused p1_scatter + h1 MFMA, roles interleaved proportionally.
struct H1S {
    _Float16 w1t[16][264];    // W1^T f16, padded row stride (528B, 16B-mult)
    _Float16 hst[4][16][16];  // per-wave row staging for packed writeout
};

__global__ __launch_bounds__(256) void p1h1_kernel(
    const int* __restrict__ ei, int E, int* __restrict__ bkt_cur,
    int* __restrict__ coarse, int nS, int h1blk, int capb,
    const float* __restrict__ x, const float* __restrict__ W1,
    uint4* __restrict__ h1h, int n) {
    __shared__ union __align__(16) { int hist[512]; H1S h1; } sm;
    int t = threadIdx.x;
    int bid = blockIdx.x;
    int total = nS + h1blk;
    // proportional role interleave: block bid is an h1 block iff
    // floor((bid+1)*h1blk/total) > floor(bid*h1blk/total).
    int f0 = (int)(((long long)bid * h1blk) / total);
    int f1 = (int)(((long long)(bid + 1) * h1blk) / total);
    if (f1 == f0) {
        // ---------------- p1 scatter (edges in registers) ----------------
        int sb = bid - f0;
        int base = sb * P1_CHUNK;
        int sarr[KITER], darr[KITER];
        for (int i = t; i < 512; i += 256) sm.hist[i] = 0;
        bool e4 = ((E & 3) == 0);
#pragma unroll
        for (int k = 0; k < KITER / 4; ++k) {
            int idx = base + (k * 256 + t) * 4;
            if (e4 && idx + 3 < E) {
                int4 s4 = *(const int4*)&ei[idx];
                int4 d4 = *(const int4*)&ei[E + idx];
                sarr[4 * k] = s4.x; sarr[4 * k + 1] = s4.y;
                sarr[4 * k + 2] = s4.z; sarr[4 * k + 3] = s4.w;
                darr[4 * k] = d4.x; darr[4 * k + 1] = d4.y;
                darr[4 * k + 2] = d4.z; darr[4 * k + 3] = d4.w;
            } else {
#pragma unroll
                for (int j = 0; j < 4; ++j) {
                    int id2 = idx + j;
                    if (id2 < E) { sarr[4 * k + j] = ei[id2]; darr[4 * k + j] = ei[E + id2]; }
                    else darr[4 * k + j] = -1;
                }
            }
        }
        __syncthreads();
#pragma unroll
        for (int k = 0; k < KITER; ++k)
            if (darr[k] >= 0) atomicAdd(&sm.hist[darr[k] >> 8], 1);
        __syncthreads();
        for (int b = t; b < 512; b += 256) {
            int c = sm.hist[b];
            sm.hist[b] = c ? atomicAdd(&bkt_cur[b], c) : 0;
        }
        __syncthreads();
#pragma unroll
        for (int k = 0; k < KITER; ++k) {
            int d = darr[k];
            if (d >= 0) {
                int bk = d >> 8;
                int pos = atomicAdd(&sm.hist[bk], 1);
                if (capb) pos = min(pos, (bk + 1) * capb - 1);  // unreachable guard
                coarse[pos] = (sarr[k] << 8) | (d & 255);
            }
        }
    } else {
        // ---------------- h1 MFMA (R2-proven form) ----------------
        int hb = f0;
        {
            const float* row = W1 + t * HID;  // t = k index 0..255
#pragma unroll
            for (int nn2 = 0; nn2 < 16; ++nn2)
                sm.h1.w1t[nn2][t] = (_Float16)row[nn2];
        }
        __syncthreads();
        int lane = t & 63, wave = t >> 6;
        int q = lane >> 4, nn = lane & 15;
#pragma unroll 1
        for (int it = 0; it < 4; ++it) {
            int nb = hb * 256 + wave * 64 + it * 16;
            int node = nb + nn;
            const float* xr = x + (size_t)min(node, n - 1) * DIM;
            float4 st[16];
#pragma unroll
            for (int s = 0; s < 8; ++s) {
                int kb = s * 32 + q * 8;
                st[2 * s]     = *(const float4*)(xr + kb);
                st[2 * s + 1] = *(const float4*)(xr + kb + 4);
            }
            f32x4 acc = {0.f, 0.f, 0.f, 0.f};
#pragma unroll
            for (int s = 0; s < 8; ++s) {
                int kb = s * 32 + q * 8;
                f16x8 bf = *(const f16x8*)&sm.h1.w1t[nn][kb];
                float4 a0 = st[2 * s], a1 = st[2 * s + 1];
                f16x8 af;
                af[0] = (_Float16)a0.x; af[1] = (_Float16)a0.y;
                af[2] = (_Float16)a0.z; af[3] = (_Float16)a0.w;
                af[4] = (_Float16)a1.x; af[5] = (_Float16)a1.y;
                af[6] = (_Float16)a1.z; af[7] = (_Float16)a1.w;
                acc = __builtin_amdgcn_mfma_f32_16x16x32_f16(af, bf, acc, 0, 0, 0);
            }
            if (nb < n) {  // wave-uniform
                // D[row=q*4+r][col=nn]; row = node-in-tile, col = j.
#pragma unroll
                for (int r = 0; r < 4; ++r)
                    sm.h1.hst[wave][q * 4 + r][nn] = (_Float16)acc[r];
                __builtin_amdgcn_s_waitcnt(0);  // drain ds_writes (wave-lockstep)
                if (lane < 32) {
                    int nl = lane >> 1, jq = lane & 1;
                    int nd = nb + nl;
                    if (nd < n)
                        h1h[(size_t)nd * 2 + jq] = *(const uint4*)&sm.h1.hst[wave][nl][jq * 8];
                }
            }
        }
    }
}

// p2: per-bucket fine sort staged in LDS -> coalesced csr writeout.
// 512 threads; capb path computes compact bases via in-block scan of bkt_cur.
__global__ __launch_bounds__(512) void p2_fine(const int* __restrict__ coarse,
                                               const int* __restrict__ bkt_base,
                                               const int* __restrict__ bkt_cnt,
                                               const int* __restrict__ bkt_cur,
                                               int* __restrict__ csr, int* __restrict__ row_ptr,
                                               int* __restrict__ deg, int n, int capb) {
    __shared__ int cnt[256];
    __shared__ int off[256];
    __shared__ int csr_loc[CAP];
    int b = blockIdx.x;
    int t = threadIdx.x;
    int m, wbase;
    if (capb) {
        // in-block exclusive scan of per-bucket counts (all 512 buckets)
        int* sc = csr_loc;  // reuse before sort phase
        int cv = bkt_cur[t] - t * capb;
        sc[t] = cv;
        __syncthreads();
        for (int o = 1; o < 512; o <<= 1) {
            int xg = (t >= o) ? sc[t - o] : 0;
            __syncthreads();
            sc[t] += xg;
            __syncthreads();
        }
        m = bkt_cur[b] - b * capb;
        wbase = sc[b] - m;
        __syncthreads();
    } else {
        m = bkt_cnt[b];
        wbase = bkt_base[b];
    }
    int rbase = capb ? b * capb : wbase;
    if (t < 256) cnt[t] = 0;
    __syncthreads();
    for (int i = t; i < m; i += 512) atomicAdd(&cnt[coarse[rbase + i] & 255], 1);
    __syncthreads();
    int v = 0;
    if (t < 256) { v = cnt[t]; off[t] = v; }
    __syncthreads();
    for (int o = 1; o < 256; o <<= 1) {
        int xg = (t >= o && t < 256) ? off[t - o] : 0;
        __syncthreads();
        if (t < 256) off[t] += xg;
        __syncthreads();
    }
    if (t < 256) {
        int excl = off[t] - v;
        int node = b * 256 + t;
        if (node < n) {
            row_ptr[node] = wbase + excl;
            deg[node] = v;
        }
        cnt[t] = excl;  // local cursor
    }
    __syncthreads();
    if (m <= CAP) {
        for (int i = t; i < m; i += 512) {
            int rec = coarse[rbase + i];
            int pos = atomicAdd(&cnt[rec & 255], 1);
            csr_loc[pos] = rec >> 8;
        }
        __syncthreads();
        for (int i = t; i < m; i += 512) csr[wbase + i] = csr_loc[i];
    } else {  // never expected; correctness fallback
        for (int i = t; i < m; i += 512) {
            int rec = coarse[rbase + i];
            int pos = atomicAdd(&cnt[rec & 255], 1);
            csr[wbase + pos] = rec >> 8;
        }
    }
}

// ---- aggregation core -----------------------------------------------------

// Node record: 32B = h f16x16 (stride 2 uint4). 16 lanes/node =
// (eq 0..7 edge-slot) x (jq 0..1 row-half). RECOMPUTE-as: per edge,
// as[s] = dot(h[s], a_s) = 8-FMA half-dot + shfl_xor(1) on the row we
// gather anyway -> 1 random line/edge instead of 2. aw/dw = this lane's
// jq-half of the alpha-src / alpha-dst vectors.
__device__ __forceinline__ void agg_core(
    const uint4* __restrict__ hh, const float* aw, const float* dw,
    int node, int start, int cnt, const int* __restrict__ csr,
    int lg, int eq, int jq, int gbase, float* acc, float* hs, float& denomv) {
    unpack_half8(hh[(size_t)node * 2 + jq], hs);
    float asn = 0.f, adn = 0.f;
#pragma unroll
    for (int i = 0; i < 8; ++i) { asn += hs[i] * aw[i]; adn += hs[i] * dw[i]; }
    asn += __shfl_xor(asn, 1, 64);
    adn += __shfl_xor(adn, 1, 64);
    float adi = adn;
    float w0 = __expf(lrelu(asn + adi));
    float w0s = (eq == 0) ? w0 : 0.f;
#pragma unroll
    for (int i = 0; i < 8; ++i) acc[i] = w0s * hs[i];
    float denom = w0s;
    int svA = (lg < cnt) ? csr[start + lg] : 0;
    int svB = (16 + lg < cnt) ? csr[start + 16 + lg] : 0;
#pragma unroll 1
    for (int q0 = 0; q0 < cnt; q0 += 32) {
        int nA = q0 + 32 + lg, nB = q0 + 48 + lg;
        int nsvA = (nA < cnt) ? csr[start + nA] : 0;
        int nsvB = (nB < cnt) ? csr[start + nB] : 0;
        int sl0 = gbase + eq, sl1 = gbase + 8 + eq;
        int s0 = __shfl(svA, sl0, 64);
        int s1 = __shfl(svA, sl1, 64);
        int s2 = __shfl(svB, sl0, 64);
        int s3 = __shfl(svB, sl1, 64);
        uint4 u0 = hh[(size_t)s0 * 2 + jq];
        uint4 u1 = hh[(size_t)s1 * 2 + jq];
        uint4 u2 = hh[(size_t)s2 * 2 + jq];
        uint4 u3 = hh[(size_t)s3 * 2 + jq];
        float h0[8], h1v[8], h2[8], h3[8];
        unpack_half8(u0, h0);
        unpack_half8(u1, h1v);
        unpack_half8(u2, h2);
        unpack_half8(u3, h3);
        float p0 = 0.f, p1 = 0.f, p2 = 0.f, p3 = 0.f;
#pragma unroll
        for (int i = 0; i < 8; ++i) {
            p0 += h0[i] * aw[i];
            p1 += h1v[i] * aw[i];
            p2 += h2[i] * aw[i];
            p3 += h3[i] * aw[i];
        }
        p0 += __shfl_xor(p0, 1, 64);
        p1 += __shfl_xor(p1, 1, 64);
        p2 += __shfl_xor(p2, 1, 64);
        p3 += __shfl_xor(p3, 1, 64);
        float wA = (q0 + eq < cnt)      ? __expf(lrelu(p0 + adi)) : 0.f;
        float wB = (q0 + 8 + eq < cnt)  ? __expf(lrelu(p1 + adi)) : 0.f;
        float wC = (q0 + 16 + eq < cnt) ? __expf(lrelu(p2 + adi)) : 0.f;
        float wD = (q0 + 24 + eq < cnt) ? __expf(lrelu(p3 + adi)) : 0.f;
        denom += wA + wB + wC + wD;
#pragma unroll
        for (int i = 0; i < 8; ++i)
            acc[i] += wA * h0[i] + wB * h1v[i] + wC * h2[i] + wD * h3[i];
        svA = nsvA;
        svB = nsvB;
    }
#pragma unroll
    for (int m = 2; m <= 8; m <<= 1) {
#pragma unroll
        for (int i = 0; i < 8; ++i) acc[i] += __shfl_xor(acc[i], m, 64);
        denom += __shfl_xor(denom, m, 64);
    }
    denomv = denom;
}

__global__ __launch_bounds__(256) void agg1_kernel(
    const uint4* __restrict__ hh,
    const int* __restrict__ row_ptr, const int* __restrict__ deg, const int* __restrict__ csr,
    const float* __restrict__ as1, const float* __restrict__ ad1,
    const float* __restrict__ bias, uint4* __restrict__ outh, int n) {
    int t = threadIdx.x;
    int node = blockIdx.x * 16 + (t >> 4);
    if (node >= n) return;
    int lg = t & 15, jq = lg & 1, eq = lg >> 1, gbase = t & 48;
    float aw[8], dw[8];
#pragma unroll
    for (int i = 0; i < 8; ++i) { aw[i] = as1[jq * 8 + i]; dw[i] = ad1[jq * 8 + i]; }
    float acc[8], hs[8];
    float denom;
    agg_core(hh, aw, dw, node, row_ptr[node], deg[node], csr, lg, eq, jq, gbase, acc, hs, denom);
    float inv = 1.f / denom;
    float val[8];
#pragma unroll
    for (int i = 0; i < 8; ++i) val[i] = fmaxf(acc[i] * inv + bias[jq * 8 + i], 0.f);
    if (eq == 0) outh[(size_t)node * 2 + jq] = pack_half8(val);
}

__global__ __launch_bounds__(256) void agg2_final_kernel(
    const uint4* __restrict__ hh,
    const int* __restrict__ row_ptr, const int* __restrict__ deg, const int* __restrict__ csr,
    const float* __restrict__ vsd,
    const float* __restrict__ W2, const float* __restrict__ b2,
    float* __restrict__ out, int n) {
    __shared__ float a2s[16 * HID];
    __shared__ float w2s[HID * NCLS];
    __shared__ float b2s[NCLS];
    int t = threadIdx.x;
    for (int i = t; i < HID * NCLS; i += 256) w2s[i] = W2[i];
    if (t < NCLS) b2s[t] = b2[t];
    int g = t >> 4;
    int node = blockIdx.x * 16 + g;
    int lg = t & 15, jq = lg & 1, eq = lg >> 1, gbase = t & 48;
    if (node < n) {
        float aw[8], dw[8];
#pragma unroll
        for (int i = 0; i < 8; ++i) { aw[i] = vsd[jq * 8 + i]; dw[i] = vsd[16 + jq * 8 + i]; }
        float acc[8], hs[8];
        float denom;
        agg_core(hh, aw, dw, node, row_ptr[node], deg[node], csr, lg, eq, jq, gbase, acc, hs, denom);
        float inv = 1.f / denom;
        if (eq == 0) {
            float* dst = &a2s[g * HID + jq * 8];
            *(float4*)dst = make_float4(acc[0] * inv, acc[1] * inv, acc[2] * inv, acc[3] * inv);
            *(float4*)(dst + 4) = make_float4(acc[4] * inv, acc[5] * inv, acc[6] * inv, acc[7] * inv);
        }
    }
    __syncthreads();
    int wv = t >> 6;
    int c = t & 63;
#pragma unroll
    for (int i = 0; i < 4; ++i) {
        int nl = i * 4 + wv;
        int gn = blockIdx.x * 16 + nl;
        if (gn >= n) continue;
        const float* ar = &a2s[nl * HID];
        float v = b2s[c];
#pragma unroll
        for (int j = 0; j < HID; ++j) v += ar[j] * w2s[j * NCLS + c];
        float mx = v;
#pragma unroll
        for (int off = 1; off < 64; off <<= 1) mx = fmaxf(mx, __shfl_xor(mx, off, 64));
        float ex = __expf(v - mx);
        float s = ex;
#pragma unroll
        for (int off = 1; off < 64; off <<= 1) s += __shfl_xor(s, off, 64);
        out[(size_t)gn * NCLS + c] = (v - mx) - __logf(s);
    }
}

extern "C" void kernel_launch(void* const* d_in, const int* in_sizes, int n_in,
                              void* d_out, int out_size, void* d_ws, size_t ws_size,
                              hipStream_t stream) {
    const float* x    = (const float*)d_in[0];
    const int*   ei   = (const int*)d_in[1];  // [2,E]: [0..E)=src, [E..2E)=dst
    const float* W1   = (const float*)d_in[2];
    const float* a_s1 = (const float*)d_in[3];
    const float* a_d1 = (const float*)d_in[4];
    const float* b1   = (const float*)d_in[5];
    const float* W2   = (const float*)d_in[6];
    const float* a_s2 = (const float*)d_in[7];
    const float* a_d2 = (const float*)d_in[8];
    const float* b2   = (const float*)d_in[9];
    float* out = (float*)d_out;

    const int N = in_sizes[0] / DIM;
    const int E = in_sizes[1] / 2;
    const int NB = (N + 255) >> 8;
    const int nS = (E + P1_CHUNK - 1) / P1_CHUNK;
    const int h1blk = (N + 255) / 256;

    char* p = (char*)d_ws;
    auto alloc = [&](size_t bytes) {
        char* r = p;
        p += (bytes + 255) & ~(size_t)255;
        return r;
    };
    int*   bkt_cnt  = (int*)alloc(512 * 4);
    int*   bkt_base = (int*)alloc(512 * 4);
    int*   bkt_cur  = (int*)alloc(512 * 4);
    int*   csr      = (int*)alloc((size_t)E * 4);
    int*   row_ptr  = (int*)alloc((size_t)N * 4);
    int*   deg      = (int*)alloc((size_t)N * 4);
    float* vsd      = (float*)alloc(32 * 4);
    uint4* h1h      = (uint4*)alloc((size_t)N * 32);   // 32B node records
    uint4* hreluh   = (uint4*)alloc((size_t)N * 32);

    // coarse buffer: padded layout (no pre-histogram) if workspace allows.
    int capb = 10240;  // mean bucket ~8192, sd ~90 -> 22 sigma headroom
    size_t used = (size_t)(p - (char*)d_ws);
    size_t pad_bytes = (size_t)512 * capb * 4;
    int* coarse;
    if (ws_size - used >= pad_bytes) {
        coarse = (int*)alloc(pad_bytes);
    } else {
        capb = 0;  // classic prescan fallback
        coarse = (int*)alloc((size_t)E * 4);
    }

    vsd_kernel<<<1, 512, 0, stream>>>(W2, a_s2, a_d2, vsd, bkt_cnt, bkt_cur, capb);
    if (!capb) {
        p0_hist<<<nS, 256, 0, stream>>>(ei + E, E, bkt_cnt);
        scanb<<<1, 512, 0, stream>>>(bkt_cnt, bkt_cur, bkt_base, NB);
    }
    p1h1_kernel<<<nS + h1blk, 256, 0, stream>>>(ei, E, bkt_cur, coarse, nS, h1blk, capb,
                                                x, W1, h1h, N);
    p2_fine<<<NB, 512, 0, stream>>>(coarse, bkt_base, bkt_cnt, bkt_cur,
                                    csr, row_ptr, deg, N, capb);
    agg1_kernel<<<(N + 15) / 16, 256, 0, stream>>>(h1h, row_ptr, deg, csr,
                                                   a_s1, a_d1, b1, hreluh, N);
    agg2_final_kernel<<<(N + 15) / 16, 256, 0, stream>>>(hreluh, row_ptr, deg, csr,
                                                         vsd, W2, b2, out, N);
}